// Round 15
// baseline (2239.235 us; speedup 1.0000x reference)
//
#include <hip/hip_runtime.h>

// ObjectMsgEncoder on MI355X. f32 I/O, bf16 MFMA internally (f32 accumulate).
// R14 -> R15: occupancy was VGPR-capped all along (m69 rule: waves/CU halve at
// vgpr 64/128/256; R9 vgpr64->16 waves, R12 vgpr92->8, R14 vgpr128->8).
// Combine the two proven wins:
//  * k_mega: back to R10 tile (j-tile=1, 32 rows, wave = 32-col slice,
//    kt-chunk-4 -> measured VGPR 60) + R14's ping-pong LDS (Xa rlf 16KB,
//    Yb rlf_lin/resa 16KB, 2 barriers/layer). Target: 2 blocks/CU AND
//    halved barriers. Stats live in Xa pad rows (Xa dead after S5).
//  * k_rec: R14 ping-pong version unchanged.

typedef __attribute__((ext_vector_type(8))) short short8;
typedef __attribute__((ext_vector_type(4))) float f32x4;

__device__ __forceinline__ float b2f(unsigned short u){
  union { unsigned int i; float f; } v; v.i = ((unsigned int)u) << 16; return v.f;
}
__device__ __forceinline__ unsigned short f2b(float f){
  union { float f; unsigned int i; } v; v.f = f;
  unsigned int i = v.i;
  unsigned int r = (i + 0x7FFFu + ((i >> 16) & 1u)) >> 16;
  return (unsigned short)r;
}
__device__ __forceinline__ float sigm(float x){ return 1.f/(1.f+__expf(-x)); }
__device__ __forceinline__ float tanh_f(float x){ float e = __expf(2.f*x); return 1.f - 2.f/(e+1.f); }
// swizzle: 8-element (16B) chunks, phys chunk = (c&24) | ((c^row)&7).
__device__ __forceinline__ int xsw(int row, int n){
  int c = n >> 3;
  int pc = (c & 24) | ((c ^ row) & 7);
  return row*256 + pc*8 + (n & 7);
}
__device__ __forceinline__ int xchunk(int row, int c){
  return row*256 + ((c & 24) | ((c ^ row) & 7))*8;
}

#define MFMA16(a,b,c) __builtin_amdgcn_mfma_f32_16x16x32_bf16((a),(b),(c),0,0,0)

// ---------------- K0: f32 -> bf16 conversion of all 5 weight matrices ----------------
__global__ __launch_bounds__(256) void k_cvt5(const float* __restrict__ s0,
                                              const float* __restrict__ s1,
                                              const float* __restrict__ s2,
                                              const float* __restrict__ s3,
                                              const float* __restrict__ s4,
                                              unsigned short* __restrict__ dst){
  int i = blockIdx.x*256 + threadIdx.x;   // grid 3328*256 = 851,968 exactly
  const float* s; int off;
  if      (i < 262144){ s = s0; off = 0; }
  else if (i < 524288){ s = s1; off = 262144; }
  else if (i < 720896){ s = s2; off = 524288; }
  else if (i < 786432){ s = s3; off = 720896; }
  else                { s = s4; off = 786432; }
  dst[i] = f2b(s[i - off]);
}

// ---------------- K1: olf0 = emb * mask (f32 -> bf16) + zero outacc ----------------
__global__ __launch_bounds__(256) void k_prep(const float* __restrict__ emb,
                                              const int* __restrict__ counts,
                                              unsigned short* __restrict__ olf,
                                              float* __restrict__ outacc){
  int bs = blockIdx.x;            // b*28+s
  int b = bs / 28; int s = bs - b*28;
  int e = threadIdx.x;
  olf[(size_t)bs*256 + e] = (s < counts[b]) ? f2b(emb[(size_t)bs*256 + e]) : (unsigned short)0;
  outacc[(size_t)bs*256 + e] = 0.f;
}

// ---------------- K2a: zx = olf_l @ Wih^T  [7168,256]@[256,1024] -> bf16 ----------------
__global__ __launch_bounds__(256) void k_xgemm(const unsigned short* __restrict__ olf,
                                               const unsigned short* __restrict__ Wih,
                                               unsigned short* __restrict__ zx){
  const int tid = threadIdx.x;
  const int wid = tid >> 6, lane = tid & 63, col = lane & 15, quad = lane >> 4;
  const int m0 = blockIdx.x*64 + wid*16;
  short8 af[8];
  #pragma unroll
  for (int kt=0; kt<8; ++kt)
    af[kt] = *(const short8*)&olf[(size_t)(m0 + col)*256 + kt*32 + quad*8];
  #pragma unroll 4
  for (int nt=0; nt<64; ++nt){
    int n = nt*16 + col;
    f32x4 acc = (f32x4){0.f,0.f,0.f,0.f};
    #pragma unroll
    for (int kt=0; kt<8; ++kt){
      short8 bf = *(const short8*)&Wih[(size_t)n*256 + kt*32 + quad*8];
      acc = MFMA16(af[kt], bf, acc);
    }
    #pragma unroll
    for (int r=0; r<4; ++r)
      zx[(size_t)(m0 + quad*4 + r)*1024 + n] = f2b(acc[r]);
  }
}

// ---------------- K2b: LSTM recurrence (16 blocks x 16 scenes, ping-pong h) ----------------
__global__ __launch_bounds__(512) void k_rec(const unsigned short* __restrict__ zx,
                                             const unsigned short* __restrict__ Whh,
                                             const float* __restrict__ bih,
                                             const float* __restrict__ bhh,
                                             const int* __restrict__ counts,
                                             unsigned short* __restrict__ olf_out){
  __shared__ unsigned short Ab[2][16*264];   // ping-pong h buffers
  const int tid = threadIdx.x;
  const int wid = tid >> 6, lane = tid & 63, col = lane & 15, quad = lane >> 4;
  const int sc0 = blockIdx.x * 16;

  float bz[4][2];
  #pragma unroll
  for (int g=0; g<4; ++g){
    #pragma unroll
    for (int tt=0; tt<2; ++tt){
      int u = wid*32 + tt*16 + col;
      bz[g][tt] = bih[g*256+u] + bhh[g*256+u];
    }
  }
  int cnt4[4];
  #pragma unroll
  for (int r=0; r<4; ++r) cnt4[r] = counts[sc0 + quad*4 + r];

  float cst[2][4];
  #pragma unroll
  for (int tt=0; tt<2; ++tt){
    #pragma unroll
    for (int r=0; r<4; ++r) cst[tt][r] = 0.f;
  }
  for (int i=tid; i<16*264; i+=512) Ab[0][i] = 0;   // h0 = 0
  __syncthreads();

  for (int t=0; t<28; ++t){
    const int cur = t & 1, nxt = cur ^ 1;
    float zxv[4][2][4];
    #pragma unroll
    for (int g=0; g<4; ++g){
      #pragma unroll
      for (int tt=0; tt<2; ++tt){
        #pragma unroll
        for (int r=0; r<4; ++r)
          zxv[g][tt][r] = b2f(zx[((size_t)(sc0 + quad*4 + r)*28 + t)*1024
                                 + g*256 + wid*32 + tt*16 + col]);
      }
    }
    f32x4 acc[4][2];
    #pragma unroll
    for (int g=0; g<4; ++g){
      #pragma unroll
      for (int tt=0; tt<2; ++tt) acc[g][tt] = (f32x4){0.f,0.f,0.f,0.f};
    }
    #pragma unroll
    for (int kt=0; kt<8; ++kt){
      short8 a = *(const short8*)&Ab[cur][col*264 + kt*32 + quad*8];
      #pragma unroll
      for (int g=0; g<4; ++g){
        #pragma unroll
        for (int tt=0; tt<2; ++tt){
          int n = g*256 + wid*32 + tt*16 + col;
          short8 bf = *(const short8*)&Whh[(size_t)n*256 + kt*32 + quad*8];
          acc[g][tt] = MFMA16(a, bf, acc[g][tt]);
        }
      }
    }
    // no barrier: writes go to Ab[nxt], readers use Ab[cur]
    #pragma unroll
    for (int tt=0; tt<2; ++tt){
      #pragma unroll
      for (int r=0; r<4; ++r){
        int s = quad*4 + r;
        int u = wid*32 + tt*16 + col;
        float zi = acc[0][tt][r] + zxv[0][tt][r] + bz[0][tt];
        float zf = acc[1][tt][r] + zxv[1][tt][r] + bz[1][tt];
        float zg = acc[2][tt][r] + zxv[2][tt][r] + bz[2][tt];
        float zo = acc[3][tt][r] + zxv[3][tt][r] + bz[3][tt];
        float cc = sigm(zf)*cst[tt][r] + sigm(zi)*tanh_f(zg);
        cst[tt][r] = cc;
        float hh = sigm(zo)*tanh_f(cc);
        unsigned short hb = f2b(hh);
        Ab[nxt][s*264 + u] = hb;                              // raw h feeds recurrence
        olf_out[((size_t)(sc0+s)*28 + t)*256 + u] = (t < cnt4[r]) ? hb : (unsigned short)0;
      }
    }
    __syncthreads();   // Ab[nxt] complete before step t+1 reads it
  }
}

// ---------------- K3: A-terms, [21504,256]@[256,512] -> bf16 ----------------
__global__ __launch_bounds__(256) void k_aterm(const unsigned short* __restrict__ olf,
                                               const unsigned short* __restrict__ Wgr,
                                               unsigned short* __restrict__ Aout){
  const int tid = threadIdx.x;
  const int wid = tid >> 6, lane = tid & 63, col = lane & 15, quad = lane >> 4;
  const int m0 = blockIdx.x*64 + wid*16;
  short8 af[8];
  #pragma unroll
  for (int kt=0; kt<8; ++kt)
    af[kt] = *(const short8*)&olf[(size_t)(m0 + col)*256 + kt*32 + quad*8];
  #pragma unroll 4
  for (int nt=0; nt<32; ++nt){
    int n = nt*16 + col;   // n<256: A_i (Wgr cols 0..255); else A_j (cols 256..511)
    const unsigned short* wb = (nt < 16) ? (Wgr + n*768) : (Wgr + (n-256)*768 + 256);
    f32x4 acc = (f32x4){0.f,0.f,0.f,0.f};
    #pragma unroll
    for (int kt=0; kt<8; ++kt){
      short8 bf = *(const short8*)&wb[kt*32 + quad*8];
      acc = MFMA16(af[kt], bf, acc);
    }
    #pragma unroll
    for (int r=0; r<4; ++r)
      Aout[(size_t)(m0 + quad*4 + r)*512 + nt*16 + col] = f2b(acc[r]);
  }
}

// ---------------- K4: fused per-(scene, single-j), ping-pong LDS ----------------
// 7168 blocks x 512 thr (8 waves). 28 rows padded to 32. Wave wv owns cols
// wv*32..+31 for all 32 rows (2 row-frags x 2 col-frags, kt chunks of 4 ->
// 16 frags in flight, R10-measured VGPR 60). Xa = rlf (16,384 B), Yb =
// rlf_lin/resa (16,384 B): 32,768 B total -> 2 blocks/CU at <=64 VGPR.
#define GEMM_TILE(SRC, WPTR, WSTRIDE, WOFF)                                         \
  {                                                                                 \
    Ya[0][0]=Ya[0][1]=Ya[1][0]=Ya[1][1]=(f32x4){0.f,0.f,0.f,0.f};                   \
    _Pragma("unroll 1")                                                             \
    for (int kc=0; kc<2; ++kc){                                                     \
      short8 av0[4], av1[4], bv0[4], bv1[4];                                        \
      _Pragma("unroll")                                                             \
      for (int u=0; u<4; ++u){                                                      \
        int kt = kc*4 + u; int c = kt*4 + quad;                                     \
        av0[u] = *(const short8*)&(SRC)[xchunk(col, c)];                            \
        av1[u] = *(const short8*)&(SRC)[xchunk(16+col, c)];                         \
        bv0[u] = *(const short8*)&(WPTR)[(nbase+col)*(WSTRIDE) + (WOFF) + kt*32 + quad*8];      \
        bv1[u] = *(const short8*)&(WPTR)[(nbase+16+col)*(WSTRIDE) + (WOFF) + kt*32 + quad*8];   \
      }                                                                             \
      _Pragma("unroll")                                                             \
      for (int u=0; u<4; ++u){                                                      \
        Ya[0][0] = MFMA16(av0[u], bv0[u], Ya[0][0]);                                \
        Ya[1][0] = MFMA16(av1[u], bv0[u], Ya[1][0]);                                \
        Ya[0][1] = MFMA16(av0[u], bv1[u], Ya[0][1]);                                \
        Ya[1][1] = MFMA16(av1[u], bv1[u], Ya[1][1]);                                \
      }                                                                             \
    }                                                                               \
  }

__global__ __launch_bounds__(512) void k_mega(
    const float* __restrict__ centers, const int* __restrict__ counts,
    const float* __restrict__ Wr, const float* __restrict__ br,
    const unsigned short* __restrict__ Wgr, const float* __restrict__ bgr,
    const unsigned short* __restrict__ Wbc, const float* __restrict__ bbc,
    const float* __restrict__ alpha,
    const unsigned short* __restrict__ Wesa, const float* __restrict__ besa,
    const float* __restrict__ Wmu, const float* __restrict__ bmu,
    const unsigned short* __restrict__ Aterm, float* __restrict__ outacc){
  __shared__ unsigned short Xa[32*256];    // rlf; rows 28..31 pad -> stats later
  __shared__ unsigned short Yb[32*256];    // rlf_lin / resa
  float* lseBp = (float*)&Xa[28*256];      // 256 f32 (rows 28-29)
  float* gsbp  = (float*)&Xa[30*256];      // 32 f32
  float* lseGp = (float*)&Xa[30*256 + 64]; // 1 f32
  const int tid = threadIdx.x;
  const int wv = tid >> 6;          // 0..7 -> col slice
  const int lane = tid & 63, col = lane & 15, quad = lane >> 4;
  const int b = blockIdx.x / 28, j = blockIdx.x - b*28;
  const int cb = counts[b];
  const int nbase = wv*32;

  float av_ = alpha[0];
  float tv = sigm(av_);
  float c1 = (1.f-tv)*(1.f-tv) + tv*tv;
  float c2 = 2.f*tv*(1.f-tv);

  int pis[2][4]; float pv[2][4];
  #pragma unroll
  for (int rf=0; rf<2; ++rf){
    #pragma unroll
    for (int r=0; r<4; ++r){
      int i = rf*16 + quad*4 + r;
      pis[rf][r] = (i < 27) ? i : 27;
      pv[rf][r] = (i < 28 && i < cb && j < cb) ? 1.f : 0.f;
    }
  }
  // S0: rlf0[i] -> Xa ; pad rows = 0
  {
    int m = tid >> 4, sub = tid & 15;  // m 0..31, 16 cols each
    bool valid = (m < 28);
    float mi = (valid && m < cb) ? 1.f : 0.f;
    float mj = (valid && j < cb) ? 1.f : 0.f;
    const float* ci = centers + (b*28 + (valid ? m : 0))*3;
    const float* cj = centers + (b*28 + j)*3;
    float dx = mi*ci[0] - mj*cj[0];
    float dy = mi*ci[1] - mj*cj[1];
    float dz = mi*ci[2] - mj*cj[2];
    for (int e = sub*16; e < sub*16 + 16; ++e){
      float v = valid ? (dx*Wr[e*3] + dy*Wr[e*3+1] + dz*Wr[e*3+2] + br[e]) : 0.f;
      Xa[xsw(m, e)] = f2b(v);
    }
  }
  __syncthreads();

  f32x4 Ya[2][2];
  #pragma unroll 1
  for (int l=0; l<3; ++l){
    // GEMM1: rlf(Xa) @ Wgr_r^T -- then S2 writes Yb (no barrier in between)
    GEMM_TILE(Xa, Wgr, 768, 512);
    // S2: rlf_lin = Y + A_i + A_j + bgr -> Yb (bf16)
    int aib[2][4];
    #pragma unroll
    for (int rf=0; rf<2; ++rf)
      #pragma unroll
      for (int r=0; r<4; ++r) aib[rf][r] = (l*7168 + b*28 + pis[rf][r])*512;
    const int ajb = (l*7168 + b*28 + j)*512 + 256;
    #pragma unroll
    for (int nt=0; nt<2; ++nt){
      int n = nbase + nt*16 + col;
      float bg = bgr[n];
      float aj = b2f(Aterm[ajb + n]);
      #pragma unroll
      for (int rf=0; rf<2; ++rf){
        #pragma unroll
        for (int r=0; r<4; ++r){
          float v = Ya[rf][nt][r] + bg + b2f(Aterm[aib[rf][r] + n]) + aj;
          Yb[xsw(rf*16 + quad*4 + r, n)] = f2b(v);
        }
      }
    }
    __syncthreads();   // Yb complete before GEMM2 reads it
    // GEMM2: rlf_lin(Yb) @ Wbc^T -- then S4 writes Xa (no barrier in between)
    GEMM_TILE(Yb, Wbc, 256, 0);
    // S4: rlf = tanh(c1*rlf_lin + c2*(CP+bbc)) * pv -> Xa (rlf_lin re-read
    // from this thread's own Yb slots -- no cross-wave dependency)
    #pragma unroll
    for (int nt=0; nt<2; ++nt){
      int n = nbase + nt*16 + col;
      float bb = bbc[n];
      #pragma unroll
      for (int rf=0; rf<2; ++rf){
        #pragma unroll
        for (int r=0; r<4; ++r){
          int off = xsw(rf*16 + quad*4 + r, n);
          float rl = b2f(Yb[off]);
          float bez = c1*rl + c2*(Ya[rf][nt][r] + bb);
          Xa[off] = f2b(tanh_f(bez) * pv[rf][r]);
        }
      }
    }
    __syncthreads();   // Xa complete before next GEMM1; also fences Yb readers vs next S2
  }
  // S5: resa = rlf(Xa) @ Wesa^T + besa -> Yb
  GEMM_TILE(Xa, Wesa, 256, 0);
  #pragma unroll
  for (int nt=0; nt<2; ++nt){
    int n = nbase + nt*16 + col;
    float be = besa[n];
    #pragma unroll
    for (int rf=0; rf<2; ++rf){
      #pragma unroll
      for (int r=0; r<4; ++r)
        Yb[xsw(rf*16 + quad*4 + r, n)] = f2b(Ya[rf][nt][r] + be);
    }
  }
  __syncthreads();   // resa (Yb) complete; Xa dead -> stats go into Xa pads
  // gscore (rows < 28) + lseB per o, reading Yb
  {
    int m = tid >> 4, sub = tid & 15;
    if (m < 28){
      float s = 0.f;
      for (int e = sub*16; e < sub*16 + 16; ++e){
        float wm = Wmu[e] + Wmu[256+e] + Wmu[512+e];
        s += b2f(Yb[xsw(m, e)]) * wm;
      }
      s += __shfl_xor(s, 1, 64);
      s += __shfl_xor(s, 2, 64);
      s += __shfl_xor(s, 4, 64);
      s += __shfl_xor(s, 8, 64);
      if (sub == 0)
        gsbp[m] = s*(1.f/3.f) + (bmu[0] + bmu[1] + bmu[2])*(1.f/3.f);
    }
  }
  if (tid < 256){
    int o = tid;
    float mx = -1e30f;
    for (int i=0;i<28;++i) mx = fmaxf(mx, b2f(Yb[xsw(i, o)]));
    float se = 0.f;
    for (int i=0;i<28;++i) se += __expf(b2f(Yb[xsw(i, o)]) - mx);
    lseBp[o] = mx + __logf(se);
  }
  __syncthreads();
  if (tid == 0){
    float mx = -1e30f;
    for (int i=0;i<28;++i) mx = fmaxf(mx, gsbp[i]);
    float se = 0.f;
    for (int i=0;i<28;++i) se += __expf(gsbp[i] - mx);
    lseGp[0] = mx + __logf(se);
  }
  __syncthreads();
  // output contribution of this j: atomicAdd a*v into outacc[b][i][o]
  const float lseG = lseGp[0];
  for (int it = tid; it < 7168; it += 512){
    int i = it >> 8, o = it & 255;
    float v = b2f(Yb[xsw(i, o)]);
    float a = 0.5f*__expf(v - lseBp[o]) + 0.5f*__expf(gsbp[i] - lseG);
    atomicAdd(&outacc[((size_t)b*28 + i)*256 + o], a * v);
  }
}

// ---------------- K5: mask + write f32 ----------------
__global__ __launch_bounds__(256) void k_out(const float* __restrict__ outacc,
                                             const int* __restrict__ counts,
                                             float* __restrict__ out){
  int b = blockIdx.x / 28, i = blockIdx.x - b*28, o = threadIdx.x;
  float acc = outacc[(size_t)blockIdx.x*256 + o];
  if (i >= counts[b]) acc = 0.f;
  out[(size_t)blockIdx.x*256 + o] = acc;
}

extern "C" void kernel_launch(void* const* d_in, const int* in_sizes, int n_in,
                              void* d_out, int out_size, void* d_ws, size_t ws_size,
                              hipStream_t stream){
  const float* centers = (const float*)d_in[0];
  const float* emb     = (const float*)d_in[1];
  const int*   counts  = (const int*)d_in[2];
  const float* Wr      = (const float*)d_in[3];
  const float* br      = (const float*)d_in[4];
  const float* Wih     = (const float*)d_in[5];
  const float* Whh     = (const float*)d_in[6];
  const float* bih     = (const float*)d_in[7];
  const float* bhh     = (const float*)d_in[8];
  const float* Wgr     = (const float*)d_in[9];
  const float* bgr     = (const float*)d_in[10];
  const float* Wbc     = (const float*)d_in[11];
  const float* bbc     = (const float*)d_in[12];
  const float* alpha   = (const float*)d_in[13];
  const float* Wesa    = (const float*)d_in[14];
  const float* besa    = (const float*)d_in[15];
  const float* Wmu     = (const float*)d_in[16];
  const float* bmu     = (const float*)d_in[17];
  // d_in[18], d_in[19] (Wlv, blv) are dead at eval time.

  // ws layout (42,074,112 bytes total):
  unsigned short* olf    = (unsigned short*)d_ws;                      // 3*7168*256 bf16 = 11,010,048 B
  unsigned short* At     = (unsigned short*)((char*)d_ws + 11010048);  // 3*7168*512 bf16 = 22,020,096 B
  unsigned short* zx     = At;                                         // 7168*1024 bf16 (aliases At)
  float*          outacc = (float*)((char*)d_ws + 33030144);           // 7168*256 f32 = 7,340,032 B
  unsigned short* wcv    = (unsigned short*)((char*)d_ws + 40370176);  // 851,968 bf16 = 1,703,936 B
  unsigned short* cWih  = wcv;            // 262144
  unsigned short* cWhh  = wcv + 262144;   // 262144
  unsigned short* cWgr  = wcv + 524288;   // 196608
  unsigned short* cWbc  = wcv + 720896;   // 65536
  unsigned short* cWesa = wcv + 786432;   // 65536
  float* outp = (float*)d_out;

  hipLaunchKernelGGL(k_cvt5, dim3(3328), dim3(256), 0, stream, Wih, Whh, Wgr, Wbc, Wesa, wcv);

  hipLaunchKernelGGL(k_prep, dim3(7168), dim3(256), 0, stream, emb, counts, olf, outacc);
  // LSTM pass 1: olf0 -> olf1
  hipLaunchKernelGGL(k_xgemm, dim3(112), dim3(256), 0, stream, olf, cWih, zx);
  hipLaunchKernelGGL(k_rec,   dim3(16),  dim3(512), 0, stream, zx, cWhh, bih, bhh, counts,
                     olf + (size_t)7168*256);
  // LSTM pass 2: olf1 -> olf2
  hipLaunchKernelGGL(k_xgemm, dim3(112), dim3(256), 0, stream, olf + (size_t)7168*256, cWih, zx);
  hipLaunchKernelGGL(k_rec,   dim3(16),  dim3(512), 0, stream, zx, cWhh, bih, bhh, counts,
                     olf + (size_t)2*7168*256);
  hipLaunchKernelGGL(k_aterm, dim3(336), dim3(256), 0, stream, olf, cWgr, At);
  hipLaunchKernelGGL(k_mega,  dim3(7168), dim3(512), 0, stream,
                     centers, counts, Wr, br, cWgr, bgr, cWbc, bbc, alpha,
                     cWesa, besa, Wmu, bmu, At, outacc);
  hipLaunchKernelGGL(k_out,   dim3(7168), dim3(256), 0, stream, outacc, counts, outp);
}

// Round 16
// 1671.938 us; speedup vs baseline: 1.3393x; 1.3393x over previous
//
#include <hip/hip_runtime.h>

// ObjectMsgEncoder on MI355X. f32 I/O, bf16 MFMA internally (f32 accumulate).
// R15 -> R16: R15 regressed (ping-pong on j-tile-1 -> VGPR 76 > 64 -> back to
// 8 waves/CU with half the per-block work). Restore R14's k_mega byte-exact
// (best: 860us; j-pair + ping-pong). Attack the LSTM instead:
//  * k_rec: 512 -> 1024 thr (16 waves), wave = 16-unit tile across 4 gates
//    (32 B-frag loads/thread/step, was 64) + R14's ping-pong h (1 barrier/step).

typedef __attribute__((ext_vector_type(8))) short short8;
typedef __attribute__((ext_vector_type(4))) float f32x4;

__device__ __forceinline__ float b2f(unsigned short u){
  union { unsigned int i; float f; } v; v.i = ((unsigned int)u) << 16; return v.f;
}
__device__ __forceinline__ unsigned short f2b(float f){
  union { float f; unsigned int i; } v; v.f = f;
  unsigned int i = v.i;
  unsigned int r = (i + 0x7FFFu + ((i >> 16) & 1u)) >> 16;
  return (unsigned short)r;
}
__device__ __forceinline__ float sigm(float x){ return 1.f/(1.f+__expf(-x)); }
__device__ __forceinline__ float tanh_f(float x){ float e = __expf(2.f*x); return 1.f - 2.f/(e+1.f); }
// swizzle: 8-element (16B) chunks, phys chunk = (c&24) | ((c^row)&7).
__device__ __forceinline__ int xsw(int row, int n){
  int c = n >> 3;
  int pc = (c & 24) | ((c ^ row) & 7);
  return row*256 + pc*8 + (n & 7);
}
__device__ __forceinline__ int xchunk(int row, int c){
  return row*256 + ((c & 24) | ((c ^ row) & 7))*8;
}

#define MFMA16(a,b,c) __builtin_amdgcn_mfma_f32_16x16x32_bf16((a),(b),(c),0,0,0)

// ---------------- K0: f32 -> bf16 conversion of all 5 weight matrices ----------------
__global__ __launch_bounds__(256) void k_cvt5(const float* __restrict__ s0,
                                              const float* __restrict__ s1,
                                              const float* __restrict__ s2,
                                              const float* __restrict__ s3,
                                              const float* __restrict__ s4,
                                              unsigned short* __restrict__ dst){
  int i = blockIdx.x*256 + threadIdx.x;   // grid 3328*256 = 851,968 exactly
  const float* s; int off;
  if      (i < 262144){ s = s0; off = 0; }
  else if (i < 524288){ s = s1; off = 262144; }
  else if (i < 720896){ s = s2; off = 524288; }
  else if (i < 786432){ s = s3; off = 720896; }
  else                { s = s4; off = 786432; }
  dst[i] = f2b(s[i - off]);
}

// ---------------- K1: olf0 = emb * mask (f32 -> bf16) + zero outacc ----------------
__global__ __launch_bounds__(256) void k_prep(const float* __restrict__ emb,
                                              const int* __restrict__ counts,
                                              unsigned short* __restrict__ olf,
                                              float* __restrict__ outacc){
  int bs = blockIdx.x;            // b*28+s
  int b = bs / 28; int s = bs - b*28;
  int e = threadIdx.x;
  olf[(size_t)bs*256 + e] = (s < counts[b]) ? f2b(emb[(size_t)bs*256 + e]) : (unsigned short)0;
  outacc[(size_t)bs*256 + e] = 0.f;
}

// ---------------- K2a: zx = olf_l @ Wih^T  [7168,256]@[256,1024] -> bf16 ----------------
__global__ __launch_bounds__(256) void k_xgemm(const unsigned short* __restrict__ olf,
                                               const unsigned short* __restrict__ Wih,
                                               unsigned short* __restrict__ zx){
  const int tid = threadIdx.x;
  const int wid = tid >> 6, lane = tid & 63, col = lane & 15, quad = lane >> 4;
  const int m0 = blockIdx.x*64 + wid*16;
  short8 af[8];
  #pragma unroll
  for (int kt=0; kt<8; ++kt)
    af[kt] = *(const short8*)&olf[(size_t)(m0 + col)*256 + kt*32 + quad*8];
  #pragma unroll 4
  for (int nt=0; nt<64; ++nt){
    int n = nt*16 + col;
    f32x4 acc = (f32x4){0.f,0.f,0.f,0.f};
    #pragma unroll
    for (int kt=0; kt<8; ++kt){
      short8 bf = *(const short8*)&Wih[(size_t)n*256 + kt*32 + quad*8];
      acc = MFMA16(af[kt], bf, acc);
    }
    #pragma unroll
    for (int r=0; r<4; ++r)
      zx[(size_t)(m0 + quad*4 + r)*1024 + n] = f2b(acc[r]);
  }
}

// ---------------- K2b: LSTM recurrence: 16 blocks x 16 scenes, 1024 thr, ping-pong h ----------------
// Wave wv (0..15) owns units u = wv*16+col across all 4 gates.
__global__ __launch_bounds__(1024) void k_rec(const unsigned short* __restrict__ zx,
                                              const unsigned short* __restrict__ Whh,
                                              const float* __restrict__ bih,
                                              const float* __restrict__ bhh,
                                              const int* __restrict__ counts,
                                              unsigned short* __restrict__ olf_out){
  __shared__ unsigned short Ab[2][16*264];   // ping-pong h buffers
  const int tid = threadIdx.x;
  const int wv = tid >> 6, lane = tid & 63, col = lane & 15, quad = lane >> 4;
  const int sc0 = blockIdx.x * 16;
  const int u = wv*16 + col;

  float bz[4];
  #pragma unroll
  for (int g=0; g<4; ++g) bz[g] = bih[g*256+u] + bhh[g*256+u];
  int cnt4[4];
  #pragma unroll
  for (int r=0; r<4; ++r) cnt4[r] = counts[sc0 + quad*4 + r];

  float cst[4];
  #pragma unroll
  for (int r=0; r<4; ++r) cst[r] = 0.f;
  for (int i=tid; i<16*264; i+=1024) Ab[0][i] = 0;   // h0 = 0
  __syncthreads();

  for (int t=0; t<28; ++t){
    const int cur = t & 1, nxt = cur ^ 1;
    float zxv[4][4];
    #pragma unroll
    for (int g=0; g<4; ++g){
      #pragma unroll
      for (int r=0; r<4; ++r)
        zxv[g][r] = b2f(zx[((size_t)(sc0 + quad*4 + r)*28 + t)*1024 + g*256 + u]);
    }
    f32x4 acc[4];
    #pragma unroll
    for (int g=0; g<4; ++g) acc[g] = (f32x4){0.f,0.f,0.f,0.f};
    #pragma unroll
    for (int kt=0; kt<8; ++kt){
      short8 a = *(const short8*)&Ab[cur][col*264 + kt*32 + quad*8];
      #pragma unroll
      for (int g=0; g<4; ++g){
        short8 bf = *(const short8*)&Whh[(size_t)(g*256 + wv*16 + col)*256 + kt*32 + quad*8];
        acc[g] = MFMA16(a, bf, acc[g]);
      }
    }
    // no barrier: writes go to Ab[nxt], readers used Ab[cur]
    #pragma unroll
    for (int r=0; r<4; ++r){
      int s = quad*4 + r;
      float zi = acc[0][r] + zxv[0][r] + bz[0];
      float zf = acc[1][r] + zxv[1][r] + bz[1];
      float zg = acc[2][r] + zxv[2][r] + bz[2];
      float zo = acc[3][r] + zxv[3][r] + bz[3];
      float cc = sigm(zf)*cst[r] + sigm(zi)*tanh_f(zg);
      cst[r] = cc;
      float hh = sigm(zo)*tanh_f(cc);
      unsigned short hb = f2b(hh);
      Ab[nxt][s*264 + u] = hb;                              // raw h feeds recurrence
      olf_out[((size_t)(sc0+s)*28 + t)*256 + u] = (t < cnt4[r]) ? hb : (unsigned short)0;
    }
    __syncthreads();   // Ab[nxt] complete before step t+1 reads it
  }
}

// ---------------- K3: A-terms, [21504,256]@[256,512] -> bf16 ----------------
__global__ __launch_bounds__(256) void k_aterm(const unsigned short* __restrict__ olf,
                                               const unsigned short* __restrict__ Wgr,
                                               unsigned short* __restrict__ Aout){
  const int tid = threadIdx.x;
  const int wid = tid >> 6, lane = tid & 63, col = lane & 15, quad = lane >> 4;
  const int m0 = blockIdx.x*64 + wid*16;
  short8 af[8];
  #pragma unroll
  for (int kt=0; kt<8; ++kt)
    af[kt] = *(const short8*)&olf[(size_t)(m0 + col)*256 + kt*32 + quad*8];
  #pragma unroll 4
  for (int nt=0; nt<32; ++nt){
    int n = nt*16 + col;   // n<256: A_i (Wgr cols 0..255); else A_j (cols 256..511)
    const unsigned short* wb = (nt < 16) ? (Wgr + n*768) : (Wgr + (n-256)*768 + 256);
    f32x4 acc = (f32x4){0.f,0.f,0.f,0.f};
    #pragma unroll
    for (int kt=0; kt<8; ++kt){
      short8 bf = *(const short8*)&wb[kt*32 + quad*8];
      acc = MFMA16(af[kt], bf, acc);
    }
    #pragma unroll
    for (int r=0; r<4; ++r)
      Aout[(size_t)(m0 + quad*4 + r)*512 + nt*16 + col] = f2b(acc[r]);
  }
}

// ---------------- K4: fused per-(scene, j-pair), ping-pong LDS (R14 exact) ----------------
// 3584 blocks x 512 thr (8 waves). Row p = i*2 + jc (i<28, jc<2) -> 56 rows
// padded to 64. Wave wv owns cols wv*32..+31 for all 64 rows (4 row-frags x
// 2 col-frags, kt chunks of 2). Xa = rlf, Yb = rlf_lin/resa: 2 x 32,768 B.
#define GEMM_TILE64(SRC, WPTR, WSTRIDE, WOFF)                                       \
  {                                                                                 \
    _Pragma("unroll")                                                               \
    for (int rf=0; rf<4; ++rf){ Ya[rf][0]=(f32x4){0.f,0.f,0.f,0.f};                 \
                                Ya[rf][1]=(f32x4){0.f,0.f,0.f,0.f}; }               \
    _Pragma("unroll 1")                                                             \
    for (int kc=0; kc<4; ++kc){                                                     \
      short8 av[2][4], bv[2][2];                                                    \
      _Pragma("unroll")                                                             \
      for (int u=0; u<2; ++u){                                                      \
        int kt = kc*2 + u; int c = kt*4 + quad;                                     \
        _Pragma("unroll")                                                           \
        for (int rf=0; rf<4; ++rf)                                                  \
          av[u][rf] = *(const short8*)&(SRC)[xchunk(rf*16+col, c)];                 \
        bv[u][0] = *(const short8*)&(WPTR)[(nbase+col)*(WSTRIDE) + (WOFF) + kt*32 + quad*8];    \
        bv[u][1] = *(const short8*)&(WPTR)[(nbase+16+col)*(WSTRIDE) + (WOFF) + kt*32 + quad*8]; \
      }                                                                             \
      _Pragma("unroll")                                                             \
      for (int u=0; u<2; ++u){                                                      \
        _Pragma("unroll")                                                           \
        for (int rf=0; rf<4; ++rf){                                                 \
          Ya[rf][0] = MFMA16(av[u][rf], bv[u][0], Ya[rf][0]);                       \
          Ya[rf][1] = MFMA16(av[u][rf], bv[u][1], Ya[rf][1]);                       \
        }                                                                           \
      }                                                                             \
    }                                                                               \
  }

__global__ __launch_bounds__(512) void k_mega(
    const float* __restrict__ centers, const int* __restrict__ counts,
    const float* __restrict__ Wr, const float* __restrict__ br,
    const unsigned short* __restrict__ Wgr, const float* __restrict__ bgr,
    const unsigned short* __restrict__ Wbc, const float* __restrict__ bbc,
    const float* __restrict__ alpha,
    const unsigned short* __restrict__ Wesa, const float* __restrict__ besa,
    const float* __restrict__ Wmu, const float* __restrict__ bmu,
    const unsigned short* __restrict__ Aterm, float* __restrict__ outacc){
  __shared__ unsigned short Xa[64*256];    // rlf; rows 56..63 pad -> stats later
  __shared__ unsigned short Yb[64*256];    // rlf_lin / resa
  float* lseBp = (float*)&Xa[56*256];      // 512 f32 [jc*256+o]
  float* gsbp  = (float*)&Xa[60*256];      // 64 f32 per row p
  float* lseGp = (float*)&Xa[60*256+128];  // 2 f32 per jc
  const int tid = threadIdx.x;
  const int wv = tid >> 6;          // 0..7 -> col slice
  const int lane = tid & 63, col = lane & 15, quad = lane >> 4;
  const int b = blockIdx.x / 14, jt = blockIdx.x - b*14;   // j = jt*2 + jc
  const int cb = counts[b];
  const int nbase = wv*32;

  float av_ = alpha[0];
  float tv = sigm(av_);
  float c1 = (1.f-tv)*(1.f-tv) + tv*tv;
  float c2 = 2.f*tv*(1.f-tv);

  int pis[4][4], pjs[4][4]; float pv[4][4];
  #pragma unroll
  for (int rf=0; rf<4; ++rf){
    #pragma unroll
    for (int r=0; r<4; ++r){
      int row = rf*16 + quad*4 + r;
      int i = row >> 1;
      pis[rf][r] = (i < 27) ? i : 27;
      pjs[rf][r] = jt*2 + (row & 1);
      pv[rf][r] = (row < 56 && i < cb && pjs[rf][r] < cb) ? 1.f : 0.f;
    }
  }
  // S0: rlf0[row] -> Xa ; pad rows = 0
  {
    int m = tid >> 3, sub = tid & 7;   // m 0..63, 32 cols each
    int i = m >> 1, j = jt*2 + (m & 1);
    bool valid = (m < 56);
    float mi = (valid && i < cb) ? 1.f : 0.f;
    float mj = (valid && j < cb) ? 1.f : 0.f;
    const float* ci = centers + (b*28 + (valid ? i : 0))*3;
    const float* cj = centers + (b*28 + j)*3;
    float dx = mi*ci[0] - mj*cj[0];
    float dy = mi*ci[1] - mj*cj[1];
    float dz = mi*ci[2] - mj*cj[2];
    for (int e = sub*32; e < sub*32 + 32; ++e){
      float v = valid ? (dx*Wr[e*3] + dy*Wr[e*3+1] + dz*Wr[e*3+2] + br[e]) : 0.f;
      Xa[xsw(m, e)] = f2b(v);
    }
  }
  __syncthreads();

  f32x4 Ya[4][2];
  #pragma unroll 1
  for (int l=0; l<3; ++l){
    // GEMM1: rlf(Xa) @ Wgr_r^T  -- then S2 writes Yb (no barrier in between)
    GEMM_TILE64(Xa, Wgr, 768, 512);
    // S2: rlf_lin = Y + A_i + A_j + bgr -> Yb (bf16)
    const int lb = (l*7168 + b*28)*512;
    #pragma unroll
    for (int nt=0; nt<2; ++nt){
      int n = nbase + nt*16 + col;
      float bg = bgr[n];
      #pragma unroll
      for (int rf=0; rf<4; ++rf){
        #pragma unroll
        for (int r=0; r<4; ++r){
          float v = Ya[rf][nt][r] + bg
                  + b2f(Aterm[lb + pis[rf][r]*512 + n])
                  + b2f(Aterm[lb + pjs[rf][r]*512 + 256 + n]);
          Yb[xsw(rf*16 + quad*4 + r, n)] = f2b(v);
        }
      }
    }
    __syncthreads();   // Yb complete before GEMM2 reads it
    // GEMM2: rlf_lin(Yb) @ Wbc^T -- then S4 writes Xa (no barrier in between)
    GEMM_TILE64(Yb, Wbc, 256, 0);
    // S4: rlf = tanh(c1*rlf_lin + c2*(CP+bbc)) * pv -> Xa
    #pragma unroll
    for (int nt=0; nt<2; ++nt){
      int n = nbase + nt*16 + col;
      float bb = bbc[n];
      #pragma unroll
      for (int rf=0; rf<4; ++rf){
        #pragma unroll
        for (int r=0; r<4; ++r){
          int off = xsw(rf*16 + quad*4 + r, n);
          float rl = b2f(Yb[off]);
          float bez = c1*rl + c2*(Ya[rf][nt][r] + bb);
          Xa[off] = f2b(tanh_f(bez) * pv[rf][r]);
        }
      }
    }
    __syncthreads();   // Xa complete before next GEMM1; fences Yb readers vs next S2
  }
  // S5: resa = rlf(Xa) @ Wesa^T + besa -> Yb
  GEMM_TILE64(Xa, Wesa, 256, 0);
  #pragma unroll
  for (int nt=0; nt<2; ++nt){
    int n = nbase + nt*16 + col;
    float be = besa[n];
    #pragma unroll
    for (int rf=0; rf<4; ++rf){
      #pragma unroll
      for (int r=0; r<4; ++r)
        Yb[xsw(rf*16 + quad*4 + r, n)] = f2b(Ya[rf][nt][r] + be);
    }
  }
  __syncthreads();   // resa (Yb) complete; Xa dead -> stats go into Xa pads
  // gscore per row (rows < 56) + lseB per (jc,o), all read Yb
  {
    int m = tid >> 3, sub = tid & 7;   // 8 threads per row, 32 cols each
    if (m < 56){
      float s = 0.f;
      for (int e = sub*32; e < sub*32 + 32; ++e){
        float wm = Wmu[e] + Wmu[256+e] + Wmu[512+e];
        s += b2f(Yb[xsw(m, e)]) * wm;
      }
      s += __shfl_xor(s, 1, 64);
      s += __shfl_xor(s, 2, 64);
      s += __shfl_xor(s, 4, 64);
      if (sub == 0)
        gsbp[m] = s*(1.f/3.f) + (bmu[0] + bmu[1] + bmu[2])*(1.f/3.f);
    }
  }
  {
    int jc = tid >> 8, o = tid & 255;  // all 512 threads
    float mx = -1e30f;
    for (int i=0;i<28;++i) mx = fmaxf(mx, b2f(Yb[xsw(i*2+jc, o)]));
    float se = 0.f;
    for (int i=0;i<28;++i) se += __expf(b2f(Yb[xsw(i*2+jc, o)]) - mx);
    lseBp[jc*256 + o] = mx + __logf(se);
  }
  __syncthreads();
  if (tid < 2){
    int jc = tid;
    float mx = -1e30f;
    for (int i=0;i<28;++i) mx = fmaxf(mx, gsbp[i*2+jc]);
    float se = 0.f;
    for (int i=0;i<28;++i) se += __expf(gsbp[i*2+jc] - mx);
    lseGp[jc] = mx + __logf(se);
  }
  __syncthreads();
  // output contribution of this block's 2 j's: one atomicAdd per (i,o)
  for (int it = tid; it < 7168; it += 512){
    int i = it >> 8, o = it & 255;
    float s = 0.f;
    #pragma unroll
    for (int jc=0; jc<2; ++jc){
      int row = i*2 + jc;
      float v = b2f(Yb[xsw(row, o)]);
      float a = 0.5f*__expf(v - lseBp[jc*256+o]) + 0.5f*__expf(gsbp[row] - lseGp[jc]);
      s += a * v;
    }
    atomicAdd(&outacc[((size_t)b*28 + i)*256 + o], s);
  }
}

// ---------------- K5: mask + write f32 ----------------
__global__ __launch_bounds__(256) void k_out(const float* __restrict__ outacc,
                                             const int* __restrict__ counts,
                                             float* __restrict__ out){
  int b = blockIdx.x / 28, i = blockIdx.x - b*28, o = threadIdx.x;
  float acc = outacc[(size_t)blockIdx.x*256 + o];
  if (i >= counts[b]) acc = 0.f;
  out[(size_t)blockIdx.x*256 + o] = acc;
}

extern "C" void kernel_launch(void* const* d_in, const int* in_sizes, int n_in,
                              void* d_out, int out_size, void* d_ws, size_t ws_size,
                              hipStream_t stream){
  const float* centers = (const float*)d_in[0];
  const float* emb     = (const float*)d_in[1];
  const int*   counts  = (const int*)d_in[2];
  const float* Wr      = (const float*)d_in[3];
  const float* br      = (const float*)d_in[4];
  const float* Wih     = (const float*)d_in[5];
  const float* Whh     = (const float*)d_in[6];
  const float* bih     = (const float*)d_in[7];
  const float* bhh     = (const float*)d_in[8];
  const float* Wgr     = (const float*)d_in[9];
  const float* bgr     = (const float*)d_in[10];
  const float* Wbc     = (const float*)d_in[11];
  const float* bbc     = (const float*)d_in[12];
  const float* alpha   = (const float*)d_in[13];
  const float* Wesa    = (const float*)d_in[14];
  const float* besa    = (const float*)d_in[15];
  const float* Wmu     = (const float*)d_in[16];
  const float* bmu     = (const float*)d_in[17];
  // d_in[18], d_in[19] (Wlv, blv) are dead at eval time.

  // ws layout (42,074,112 bytes total):
  unsigned short* olf    = (unsigned short*)d_ws;                      // 3*7168*256 bf16 = 11,010,048 B
  unsigned short* At     = (unsigned short*)((char*)d_ws + 11010048);  // 3*7168*512 bf16 = 22,020,096 B
  unsigned short* zx     = At;                                         // 7168*1024 bf16 (aliases At)
  float*          outacc = (float*)((char*)d_ws + 33030144);           // 7168*256 f32 = 7,340,032 B
  unsigned short* wcv    = (unsigned short*)((char*)d_ws + 40370176);  // 851,968 bf16 = 1,703,936 B
  unsigned short* cWih  = wcv;            // 262144
  unsigned short* cWhh  = wcv + 262144;   // 262144
  unsigned short* cWgr  = wcv + 524288;   // 196608
  unsigned short* cWbc  = wcv + 720896;   // 65536
  unsigned short* cWesa = wcv + 786432;   // 65536
  float* outp = (float*)d_out;

  hipLaunchKernelGGL(k_cvt5, dim3(3328), dim3(256), 0, stream, Wih, Whh, Wgr, Wbc, Wesa, wcv);

  hipLaunchKernelGGL(k_prep, dim3(7168), dim3(256), 0, stream, emb, counts, olf, outacc);
  // LSTM pass 1: olf0 -> olf1
  hipLaunchKernelGGL(k_xgemm, dim3(112), dim3(256), 0, stream, olf, cWih, zx);
  hipLaunchKernelGGL(k_rec,   dim3(16),  dim3(1024), 0, stream, zx, cWhh, bih, bhh, counts,
                     olf + (size_t)7168*256);
  // LSTM pass 2: olf1 -> olf2
  hipLaunchKernelGGL(k_xgemm, dim3(112), dim3(256), 0, stream, olf + (size_t)7168*256, cWih, zx);
  hipLaunchKernelGGL(k_rec,   dim3(16),  dim3(1024), 0, stream, zx, cWhh, bih, bhh, counts,
                     olf + (size_t)2*7168*256);
  hipLaunchKernelGGL(k_aterm, dim3(336), dim3(256), 0, stream, olf, cWgr, At);
  hipLaunchKernelGGL(k_mega,  dim3(3584), dim3(512), 0, stream,
                     centers, counts, Wr, br, cWgr, bgr, cWbc, bbc, alpha,
                     cWesa, besa, Wmu, bmu, At, outacc);
  hipLaunchKernelGGL(k_out,   dim3(7168), dim3(256), 0, stream, outacc, counts, outp);
}

// Round 17
// 1525.178 us; speedup vs baseline: 1.4682x; 1.0962x over previous
//
#include <hip/hip_runtime.h>

// ObjectMsgEncoder on MI355X. f32 I/O, bf16 MFMA internally (f32 accumulate).
// R16 -> R17: ROOT CAUSE FOUND for the universal ~10% MfmaUtil ceiling:
// B-fragment weight loads were maximally uncoalesced (lane stride = N-row
// stride = 512B/1536B -> 64 cache lines per load instruction). k_rec's
// 31.5K cyc/step matches ~32K transactions/step exactly.
// Fix: repack ALL weights once into fragment-major layout
//   Wsw[ ((k>>3)*N + n)*8 + (k&7) ]
// so a wave's B-frag load is 4 contiguous 256B runs (16x fewer transactions).
// Seven repacked blocks: Wih, Whh, Wgr_i, Wgr_j, Wgr_r, Wbc, Wesa (same ws
// bytes). All MFMA consumers updated. Compute structure identical to R16.

typedef __attribute__((ext_vector_type(8))) short short8;
typedef __attribute__((ext_vector_type(4))) float f32x4;

__device__ __forceinline__ float b2f(unsigned short u){
  union { unsigned int i; float f; } v; v.i = ((unsigned int)u) << 16; return v.f;
}
__device__ __forceinline__ unsigned short f2b(float f){
  union { float f; unsigned int i; } v; v.f = f;
  unsigned int i = v.i;
  unsigned int r = (i + 0x7FFFu + ((i >> 16) & 1u)) >> 16;
  return (unsigned short)r;
}
__device__ __forceinline__ float sigm(float x){ return 1.f/(1.f+__expf(-x)); }
__device__ __forceinline__ float tanh_f(float x){ float e = __expf(2.f*x); return 1.f - 2.f/(e+1.f); }
// LDS swizzle: 8-element (16B) chunks, phys chunk = (c&24) | ((c^row)&7).
__device__ __forceinline__ int xsw(int row, int n){
  int c = n >> 3;
  int pc = (c & 24) | ((c ^ row) & 7);
  return row*256 + pc*8 + (n & 7);
}
__device__ __forceinline__ int xchunk(int row, int c){
  return row*256 + ((c & 24) | ((c ^ row) & 7))*8;
}

#define MFMA16(a,b,c) __builtin_amdgcn_mfma_f32_16x16x32_bf16((a),(b),(c),0,0,0)

// ---------------- K0: f32 -> bf16 + fragment-major repack ----------------
// dst[ ((k>>3)*N + n)*8 + (k&7) ] = src[n*stride + off + k],  K = 256.
__global__ __launch_bounds__(256) void k_repack(const float* __restrict__ src,
                                                unsigned short* __restrict__ dst,
                                                int N, int stride, int off){
  int i = blockIdx.x*256 + threadIdx.x;   // grid = N blocks -> i < N*256
  int n = i >> 8, k = i & 255;
  dst[(((k >> 3)*N + n) << 3) + (k & 7)] = f2b(src[n*stride + off + k]);
}

// ---------------- K1: olf0 = emb * mask (f32 -> bf16) + zero outacc ----------------
__global__ __launch_bounds__(256) void k_prep(const float* __restrict__ emb,
                                              const int* __restrict__ counts,
                                              unsigned short* __restrict__ olf,
                                              float* __restrict__ outacc){
  int bs = blockIdx.x;            // b*28+s
  int b = bs / 28; int s = bs - b*28;
  int e = threadIdx.x;
  olf[(size_t)bs*256 + e] = (s < counts[b]) ? f2b(emb[(size_t)bs*256 + e]) : (unsigned short)0;
  outacc[(size_t)bs*256 + e] = 0.f;
}

// ---------------- K2a: zx = olf_l @ Wih^T  [7168,256]@[256,1024] -> bf16 ----------------
// Wih in fragment-major layout (N=1024).
__global__ __launch_bounds__(256) void k_xgemm(const unsigned short* __restrict__ olf,
                                               const unsigned short* __restrict__ Wih,
                                               unsigned short* __restrict__ zx){
  const int tid = threadIdx.x;
  const int wid = tid >> 6, lane = tid & 63, col = lane & 15, quad = lane >> 4;
  const int m0 = blockIdx.x*64 + wid*16;
  short8 af[8];
  #pragma unroll
  for (int kt=0; kt<8; ++kt)
    af[kt] = *(const short8*)&olf[(size_t)(m0 + col)*256 + kt*32 + quad*8];
  #pragma unroll 4
  for (int nt=0; nt<64; ++nt){
    int n = nt*16 + col;
    f32x4 acc = (f32x4){0.f,0.f,0.f,0.f};
    #pragma unroll
    for (int kt=0; kt<8; ++kt){
      short8 bf = *(const short8*)&Wih[((((kt*4 + quad) << 10) + n) << 3)];
      acc = MFMA16(af[kt], bf, acc);
    }
    #pragma unroll
    for (int r=0; r<4; ++r)
      zx[(size_t)(m0 + quad*4 + r)*1024 + n] = f2b(acc[r]);
  }
}

// ---------------- K2b: LSTM recurrence: 16 blocks x 16 scenes, 1024 thr, ping-pong h ----------------
// Wave wv (0..15) owns units u = wv*16+col across all 4 gates. Whh fragment-major (N=1024).
__global__ __launch_bounds__(1024) void k_rec(const unsigned short* __restrict__ zx,
                                              const unsigned short* __restrict__ Whh,
                                              const float* __restrict__ bih,
                                              const float* __restrict__ bhh,
                                              const int* __restrict__ counts,
                                              unsigned short* __restrict__ olf_out){
  __shared__ unsigned short Ab[2][16*264];   // ping-pong h buffers
  const int tid = threadIdx.x;
  const int wv = tid >> 6, lane = tid & 63, col = lane & 15, quad = lane >> 4;
  const int sc0 = blockIdx.x * 16;
  const int u = wv*16 + col;

  float bz[4];
  #pragma unroll
  for (int g=0; g<4; ++g) bz[g] = bih[g*256+u] + bhh[g*256+u];
  int cnt4[4];
  #pragma unroll
  for (int r=0; r<4; ++r) cnt4[r] = counts[sc0 + quad*4 + r];

  float cst[4];
  #pragma unroll
  for (int r=0; r<4; ++r) cst[r] = 0.f;
  for (int i=tid; i<16*264; i+=1024) Ab[0][i] = 0;   // h0 = 0
  __syncthreads();

  for (int t=0; t<28; ++t){
    const int cur = t & 1, nxt = cur ^ 1;
    float zxv[4][4];
    #pragma unroll
    for (int g=0; g<4; ++g){
      #pragma unroll
      for (int r=0; r<4; ++r)
        zxv[g][r] = b2f(zx[((size_t)(sc0 + quad*4 + r)*28 + t)*1024 + g*256 + u]);
    }
    f32x4 acc[4];
    #pragma unroll
    for (int g=0; g<4; ++g) acc[g] = (f32x4){0.f,0.f,0.f,0.f};
    #pragma unroll
    for (int kt=0; kt<8; ++kt){
      short8 a = *(const short8*)&Ab[cur][col*264 + kt*32 + quad*8];
      #pragma unroll
      for (int g=0; g<4; ++g){
        short8 bf = *(const short8*)&Whh[((((kt*4 + quad) << 10) + g*256 + u) << 3)];
        acc[g] = MFMA16(a, bf, acc[g]);
      }
    }
    // no barrier: writes go to Ab[nxt], readers used Ab[cur]
    #pragma unroll
    for (int r=0; r<4; ++r){
      int s = quad*4 + r;
      float zi = acc[0][r] + zxv[0][r] + bz[0];
      float zf = acc[1][r] + zxv[1][r] + bz[1];
      float zg = acc[2][r] + zxv[2][r] + bz[2];
      float zo = acc[3][r] + zxv[3][r] + bz[3];
      float cc = sigm(zf)*cst[r] + sigm(zi)*tanh_f(zg);
      cst[r] = cc;
      float hh = sigm(zo)*tanh_f(cc);
      unsigned short hb = f2b(hh);
      Ab[nxt][s*264 + u] = hb;                              // raw h feeds recurrence
      olf_out[((size_t)(sc0+s)*28 + t)*256 + u] = (t < cnt4[r]) ? hb : (unsigned short)0;
    }
    __syncthreads();   // Ab[nxt] complete before step t+1 reads it
  }
}

// ---------------- K3: A-terms, [21504,256]@[256,512] -> bf16 ----------------
// Wgri/Wgrj fragment-major (N=256 each).
__global__ __launch_bounds__(256) void k_aterm(const unsigned short* __restrict__ olf,
                                               const unsigned short* __restrict__ Wgri,
                                               const unsigned short* __restrict__ Wgrj,
                                               unsigned short* __restrict__ Aout){
  const int tid = threadIdx.x;
  const int wid = tid >> 6, lane = tid & 63, col = lane & 15, quad = lane >> 4;
  const int m0 = blockIdx.x*64 + wid*16;
  short8 af[8];
  #pragma unroll
  for (int kt=0; kt<8; ++kt)
    af[kt] = *(const short8*)&olf[(size_t)(m0 + col)*256 + kt*32 + quad*8];
  #pragma unroll 4
  for (int nt=0; nt<32; ++nt){
    const unsigned short* wb = (nt < 16) ? Wgri : Wgrj;
    int nn = (nt & 15)*16 + col;           // 0..255 within the submatrix
    f32x4 acc = (f32x4){0.f,0.f,0.f,0.f};
    #pragma unroll
    for (int kt=0; kt<8; ++kt){
      short8 bf = *(const short8*)&wb[((((kt*4 + quad) << 8) + nn) << 3)];
      acc = MFMA16(af[kt], bf, acc);
    }
    #pragma unroll
    for (int r=0; r<4; ++r)
      Aout[(size_t)(m0 + quad*4 + r)*512 + nt*16 + col] = f2b(acc[r]);
  }
}

// ---------------- K4: fused per-(scene, j-pair), ping-pong LDS ----------------
// 3584 blocks x 512 thr (8 waves). Row p = i*2 + jc (i<28, jc<2) -> 56 rows
// padded to 64. Wave wv owns cols wv*32..+31 for all 64 rows (4 row-frags x
// 2 col-frags, kt chunks of 2). Xa = rlf, Yb = rlf_lin/resa: 2 x 32,768 B.
// Weights fragment-major, N=256.
#define GEMM_TILE64(SRC, WPTR)                                                      \
  {                                                                                 \
    _Pragma("unroll")                                                               \
    for (int rf=0; rf<4; ++rf){ Ya[rf][0]=(f32x4){0.f,0.f,0.f,0.f};                 \
                                Ya[rf][1]=(f32x4){0.f,0.f,0.f,0.f}; }               \
    _Pragma("unroll 1")                                                             \
    for (int kc=0; kc<4; ++kc){                                                     \
      short8 av[2][4], bv[2][2];                                                    \
      _Pragma("unroll")                                                             \
      for (int u=0; u<2; ++u){                                                      \
        int kt = kc*2 + u; int c = kt*4 + quad;                                     \
        _Pragma("unroll")                                                           \
        for (int rf=0; rf<4; ++rf)                                                  \
          av[u][rf] = *(const short8*)&(SRC)[xchunk(rf*16+col, c)];                 \
        bv[u][0] = *(const short8*)&(WPTR)[(((c << 8) + nbase + col) << 3)];        \
        bv[u][1] = *(const short8*)&(WPTR)[(((c << 8) + nbase + 16 + col) << 3)];   \
      }                                                                             \
      _Pragma("unroll")                                                             \
      for (int u=0; u<2; ++u){                                                      \
        _Pragma("unroll")                                                           \
        for (int rf=0; rf<4; ++rf){                                                 \
          Ya[rf][0] = MFMA16(av[u][rf], bv[u][0], Ya[rf][0]);                       \
          Ya[rf][1] = MFMA16(av[u][rf], bv[u][1], Ya[rf][1]);                       \
        }                                                                           \
      }                                                                             \
    }                                                                               \
  }

__global__ __launch_bounds__(512) void k_mega(
    const float* __restrict__ centers, const int* __restrict__ counts,
    const float* __restrict__ Wr, const float* __restrict__ br,
    const unsigned short* __restrict__ Wgrr, const float* __restrict__ bgr,
    const unsigned short* __restrict__ Wbc, const float* __restrict__ bbc,
    const float* __restrict__ alpha,
    const unsigned short* __restrict__ Wesa, const float* __restrict__ besa,
    const float* __restrict__ Wmu, const float* __restrict__ bmu,
    const unsigned short* __restrict__ Aterm, float* __restrict__ outacc){
  __shared__ unsigned short Xa[64*256];    // rlf; rows 56..63 pad -> stats later
  __shared__ unsigned short Yb[64*256];    // rlf_lin / resa
  float* lseBp = (float*)&Xa[56*256];      // 512 f32 [jc*256+o]
  float* gsbp  = (float*)&Xa[60*256];      // 64 f32 per row p
  float* lseGp = (float*)&Xa[60*256+128];  // 2 f32 per jc
  const int tid = threadIdx.x;
  const int wv = tid >> 6;          // 0..7 -> col slice
  const int lane = tid & 63, col = lane & 15, quad = lane >> 4;
  const int b = blockIdx.x / 14, jt = blockIdx.x - b*14;   // j = jt*2 + jc
  const int cb = counts[b];
  const int nbase = wv*32;

  float av_ = alpha[0];
  float tv = sigm(av_);
  float c1 = (1.f-tv)*(1.f-tv) + tv*tv;
  float c2 = 2.f*tv*(1.f-tv);

  int pis[4][4], pjs[4][4]; float pv[4][4];
  #pragma unroll
  for (int rf=0; rf<4; ++rf){
    #pragma unroll
    for (int r=0; r<4; ++r){
      int row = rf*16 + quad*4 + r;
      int i = row >> 1;
      pis[rf][r] = (i < 27) ? i : 27;
      pjs[rf][r] = jt*2 + (row & 1);
      pv[rf][r] = (row < 56 && i < cb && pjs[rf][r] < cb) ? 1.f : 0.f;
    }
  }
  // S0: rlf0[row] -> Xa ; pad rows = 0
  {
    int m = tid >> 3, sub = tid & 7;   // m 0..63, 32 cols each
    int i = m >> 1, j = jt*2 + (m & 1);
    bool valid = (m < 56);
    float mi = (valid && i < cb) ? 1.f : 0.f;
    float mj = (valid && j < cb) ? 1.f : 0.f;
    const float* ci = centers + (b*28 + (valid ? i : 0))*3;
    const float* cj = centers + (b*28 + j)*3;
    float dx = mi*ci[0] - mj*cj[0];
    float dy = mi*ci[1] - mj*cj[1];
    float dz = mi*ci[2] - mj*cj[2];
    for (int e = sub*32; e < sub*32 + 32; ++e){
      float v = valid ? (dx*Wr[e*3] + dy*Wr[e*3+1] + dz*Wr[e*3+2] + br[e]) : 0.f;
      Xa[xsw(m, e)] = f2b(v);
    }
  }
  __syncthreads();

  f32x4 Ya[4][2];
  #pragma unroll 1
  for (int l=0; l<3; ++l){
    // GEMM1: rlf(Xa) @ Wgr_r^T  -- then S2 writes Yb (no barrier in between)
    GEMM_TILE64(Xa, Wgrr);
    // S2: rlf_lin = Y + A_i + A_j + bgr -> Yb (bf16)
    const int lb = (l*7168 + b*28)*512;
    #pragma unroll
    for (int nt=0; nt<2; ++nt){
      int n = nbase + nt*16 + col;
      float bg = bgr[n];
      #pragma unroll
      for (int rf=0; rf<4; ++rf){
        #pragma unroll
        for (int r=0; r<4; ++r){
          float v = Ya[rf][nt][r] + bg
                  + b2f(Aterm[lb + pis[rf][r]*512 + n])
                  + b2f(Aterm[lb + pjs[rf][r]*512 + 256 + n]);
          Yb[xsw(rf*16 + quad*4 + r, n)] = f2b(v);
        }
      }
    }
    __syncthreads();   // Yb complete before GEMM2 reads it
    // GEMM2: rlf_lin(Yb) @ Wbc^T -- then S4 writes Xa (no barrier in between)
    GEMM_TILE64(Yb, Wbc);
    // S4: rlf = tanh(c1*rlf_lin + c2*(CP+bbc)) * pv -> Xa
    #pragma unroll
    for (int nt=0; nt<2; ++nt){
      int n = nbase + nt*16 + col;
      float bb = bbc[n];
      #pragma unroll
      for (int rf=0; rf<4; ++rf){
        #pragma unroll
        for (int r=0; r<4; ++r){
          int off = xsw(rf*16 + quad*4 + r, n);
          float rl = b2f(Yb[off]);
          float bez = c1*rl + c2*(Ya[rf][nt][r] + bb);
          Xa[off] = f2b(tanh_f(bez) * pv[rf][r]);
        }
      }
    }
    __syncthreads();   // Xa complete before next GEMM1; fences Yb readers vs next S2
  }
  // S5: resa = rlf(Xa) @ Wesa^T + besa -> Yb
  GEMM_TILE64(Xa, Wesa);
  #pragma unroll
  for (int nt=0; nt<2; ++nt){
    int n = nbase + nt*16 + col;
    float be = besa[n];
    #pragma unroll
    for (int rf=0; rf<4; ++rf){
      #pragma unroll
      for (int r=0; r<4; ++r)
        Yb[xsw(rf*16 + quad*4 + r, n)] = f2b(Ya[rf][nt][r] + be);
    }
  }
  __syncthreads();   // resa (Yb) complete; Xa dead -> stats go into Xa pads
  // gscore per row (rows < 56) + lseB per (jc,o), all read Yb
  {
    int m = tid >> 3, sub = tid & 7;   // 8 threads per row, 32 cols each
    if (m < 56){
      float s = 0.f;
      for (int e = sub*32; e < sub*32 + 32; ++e){
        float wm = Wmu[e] + Wmu[256+e] + Wmu[512+e];
        s += b2f(Yb[xsw(m, e)]) * wm;
      }
      s += __shfl_xor(s, 1, 64);
      s += __shfl_xor(s, 2, 64);
      s += __shfl_xor(s, 4, 64);
      if (sub == 0)
        gsbp[m] = s*(1.f/3.f) + (bmu[0] + bmu[1] + bmu[2])*(1.f/3.f);
    }
  }
  {
    int jc = tid >> 8, o = tid & 255;  // all 512 threads
    float mx = -1e30f;
    for (int i=0;i<28;++i) mx = fmaxf(mx, b2f(Yb[xsw(i*2+jc, o)]));
    float se = 0.f;
    for (int i=0;i<28;++i) se += __expf(b2f(Yb[xsw(i*2+jc, o)]) - mx);
    lseBp[jc*256 + o] = mx + __logf(se);
  }
  __syncthreads();
  if (tid < 2){
    int jc = tid;
    float mx = -1e30f;
    for (int i=0;i<28;++i) mx = fmaxf(mx, gsbp[i*2+jc]);
    float se = 0.f;
    for (int i=0;i<28;++i) se += __expf(gsbp[i*2+jc] - mx);
    lseGp[jc] = mx + __logf(se);
  }
  __syncthreads();
  // output contribution of this block's 2 j's: one atomicAdd per (i,o)
  for (int it = tid; it < 7168; it += 512){
    int i = it >> 8, o = it & 255;
    float s = 0.f;
    #pragma unroll
    for (int jc=0; jc<2; ++jc){
      int row = i*2 + jc;
      float v = b2f(Yb[xsw(row, o)]);
      float a = 0.5f*__expf(v - lseBp[jc*256+o]) + 0.5f*__expf(gsbp[row] - lseGp[jc]);
      s += a * v;
    }
    atomicAdd(&outacc[((size_t)b*28 + i)*256 + o], s);
  }
}

// ---------------- K5: mask + write f32 ----------------
__global__ __launch_bounds__(256) void k_out(const float* __restrict__ outacc,
                                             const int* __restrict__ counts,
                                             float* __restrict__ out){
  int b = blockIdx.x / 28, i = blockIdx.x - b*28, o = threadIdx.x;
  float acc = outacc[(size_t)blockIdx.x*256 + o];
  if (i >= counts[b]) acc = 0.f;
  out[(size_t)blockIdx.x*256 + o] = acc;
}

extern "C" void kernel_launch(void* const* d_in, const int* in_sizes, int n_in,
                              void* d_out, int out_size, void* d_ws, size_t ws_size,
                              hipStream_t stream){
  const float* centers = (const float*)d_in[0];
  const float* emb     = (const float*)d_in[1];
  const int*   counts  = (const int*)d_in[2];
  const float* Wr      = (const float*)d_in[3];
  const float* br      = (const float*)d_in[4];
  const float* Wih     = (const float*)d_in[5];
  const float* Whh     = (const float*)d_in[6];
  const float* bih     = (const float*)d_in[7];
  const float* bhh     = (const float*)d_in[8];
  const float* Wgr     = (const float*)d_in[9];
  const float* bgr     = (const float*)d_in[10];
  const float* Wbc     = (const float*)d_in[11];
  const float* bbc     = (const float*)d_in[12];
  const float* alpha   = (const float*)d_in[13];
  const float* Wesa    = (const float*)d_in[14];
  const float* besa    = (const float*)d_in[15];
  const float* Wmu     = (const float*)d_in[16];
  const float* bmu     = (const float*)d_in[17];
  // d_in[18], d_in[19] (Wlv, blv) are dead at eval time.

  // ws layout (42,074,112 bytes total):
  unsigned short* olf    = (unsigned short*)d_ws;                      // 3*7168*256 bf16 = 11,010,048 B
  unsigned short* At     = (unsigned short*)((char*)d_ws + 11010048);  // 3*7168*512 bf16 = 22,020,096 B
  unsigned short* zx     = At;                                         // 7168*1024 bf16 (aliases At)
  float*          outacc = (float*)((char*)d_ws + 33030144);           // 7168*256 f32 = 7,340,032 B
  unsigned short* wcv    = (unsigned short*)((char*)d_ws + 40370176);  // 851,968 bf16 = 1,703,936 B
  unsigned short* cWih  = wcv;            // 262144 (N=1024)
  unsigned short* cWhh  = wcv + 262144;   // 262144 (N=1024)
  unsigned short* cWgri = wcv + 524288;   // 65536  (N=256)
  unsigned short* cWgrj = wcv + 589824;   // 65536  (N=256)
  unsigned short* cWgrr = wcv + 655360;   // 65536  (N=256)
  unsigned short* cWbc  = wcv + 720896;   // 65536  (N=256)
  unsigned short* cWesa = wcv + 786432;   // 65536  (N=256)
  float* outp = (float*)d_out;

  // fragment-major repacks (K=256 each)
  hipLaunchKernelGGL(k_repack, dim3(1024), dim3(256), 0, stream, Wih,  cWih,  1024, 256, 0);
  hipLaunchKernelGGL(k_repack, dim3(1024), dim3(256), 0, stream, Whh,  cWhh,  1024, 256, 0);
  hipLaunchKernelGGL(k_repack, dim3(256),  dim3(256), 0, stream, Wgr,  cWgri, 256, 768, 0);
  hipLaunchKernelGGL(k_repack, dim3(256),  dim3(256), 0, stream, Wgr,  cWgrj, 256, 768, 256);
  hipLaunchKernelGGL(k_repack, dim3(256),  dim3(256), 0, stream, Wgr,  cWgrr, 256, 768, 512);
  hipLaunchKernelGGL(k_repack, dim3(256),  dim3(256), 0, stream, Wbc,  cWbc,  256, 256, 0);
  hipLaunchKernelGGL(k_repack, dim3(256),  dim3(256), 0, stream, Wesa, cWesa, 256, 256, 0);

  hipLaunchKernelGGL(k_prep, dim3(7168), dim3(256), 0, stream, emb, counts, olf, outacc);
  // LSTM pass 1: olf0 -> olf1
  hipLaunchKernelGGL(k_xgemm, dim3(112), dim3(256), 0, stream, olf, cWih, zx);
  hipLaunchKernelGGL(k_rec,   dim3(16),  dim3(1024), 0, stream, zx, cWhh, bih, bhh, counts,
                     olf + (size_t)7168*256);
  // LSTM pass 2: olf1 -> olf2
  hipLaunchKernelGGL(k_xgemm, dim3(112), dim3(256), 0, stream, olf + (size_t)7168*256, cWih, zx);
  hipLaunchKernelGGL(k_rec,   dim3(16),  dim3(1024), 0, stream, zx, cWhh, bih, bhh, counts,
                     olf + (size_t)2*7168*256);
  hipLaunchKernelGGL(k_aterm, dim3(336), dim3(256), 0, stream, olf, cWgri, cWgrj, At);
  hipLaunchKernelGGL(k_mega,  dim3(3584), dim3(512), 0, stream,
                     centers, counts, Wr, br, cWgrr, bgr, cWbc, bbc, alpha,
                     cWesa, besa, Wmu, bmu, At, outacc);
  hipLaunchKernelGGL(k_out,   dim3(7168), dim3(256), 0, stream, outacc, counts, outp);
}

// Round 18
// 1464.269 us; speedup vs baseline: 1.5293x; 1.0416x over previous
//
#include <hip/hip_runtime.h>

// ObjectMsgEncoder on MI355X. f32 I/O, bf16 MFMA internally (f32 accumulate).
// R17 -> R18: k_mega is now VALU-leading (VALUBusy 38%, MfmaUtil 11%). Cuts:
//  * f2b: 5 ops -> 2 ops (round-half-up; ties are measure-zero).
//  * softmax max-pass removed (resa is tanh-bounded -> direct sum-exp safe):
//    kills a 28-iter serial loop per thread in lseB and lseG.
//  * 7 repack launches -> 1 (k_repack7) + precomputed wmean[256] for gscore.
// Everything else byte-identical to R17 (best: 1525 us).

typedef __attribute__((ext_vector_type(8))) short short8;
typedef __attribute__((ext_vector_type(4))) float f32x4;

__device__ __forceinline__ float b2f(unsigned short u){
  union { unsigned int i; float f; } v; v.i = ((unsigned int)u) << 16; return v.f;
}
__device__ __forceinline__ unsigned short f2b(float f){
  union { float f; unsigned int i; } v; v.f = f;
  return (unsigned short)((v.i + 0x8000u) >> 16);   // round-half-up, 2 ops
}
__device__ __forceinline__ float sigm(float x){ return 1.f/(1.f+__expf(-x)); }
__device__ __forceinline__ float tanh_f(float x){ float e = __expf(2.f*x); return 1.f - 2.f/(e+1.f); }
// LDS swizzle: 8-element (16B) chunks, phys chunk = (c&24) | ((c^row)&7).
__device__ __forceinline__ int xsw(int row, int n){
  int c = n >> 3;
  int pc = (c & 24) | ((c ^ row) & 7);
  return row*256 + pc*8 + (n & 7);
}
__device__ __forceinline__ int xchunk(int row, int c){
  return row*256 + ((c & 24) | ((c ^ row) & 7))*8;
}

#define MFMA16(a,b,c) __builtin_amdgcn_mfma_f32_16x16x32_bf16((a),(b),(c),0,0,0)

// ---------------- K0: one-shot repack of all 7 weight blocks + wmean ----------------
// wcv[seg + ((k>>3)*N + n)*8 + (k&7)] = bf16(src[n*stride + off + k]); K=256.
__global__ __launch_bounds__(256) void k_repack7(const float* __restrict__ Wih,
                                                 const float* __restrict__ Whh,
                                                 const float* __restrict__ Wgr,
                                                 const float* __restrict__ Wbc,
                                                 const float* __restrict__ Wesa,
                                                 const float* __restrict__ Wmu,
                                                 unsigned short* __restrict__ wcv,
                                                 float* __restrict__ wmean){
  int i = blockIdx.x*256 + threadIdx.x;
  if (i >= 851968){                      // tail block: wmean
    int o = i - 851968;
    if (o < 256) wmean[o] = (Wmu[o] + Wmu[256+o] + Wmu[512+o]) * (1.f/3.f);
    return;
  }
  const float* s; int segbase, N, stride, off, local;
  if      (i < 262144){ s=Wih;  segbase=0;      N=1024; stride=256; off=0;   local=i; }
  else if (i < 524288){ s=Whh;  segbase=262144; N=1024; stride=256; off=0;   local=i-262144; }
  else if (i < 589824){ s=Wgr;  segbase=524288; N=256;  stride=768; off=0;   local=i-524288; }
  else if (i < 655360){ s=Wgr;  segbase=589824; N=256;  stride=768; off=256; local=i-589824; }
  else if (i < 720896){ s=Wgr;  segbase=655360; N=256;  stride=768; off=512; local=i-655360; }
  else if (i < 786432){ s=Wbc;  segbase=720896; N=256;  stride=256; off=0;   local=i-720896; }
  else                { s=Wesa; segbase=786432; N=256;  stride=256; off=0;   local=i-786432; }
  int n = local >> 8, k = local & 255;
  wcv[segbase + (((k >> 3)*N + n) << 3) + (k & 7)] = f2b(s[n*stride + off + k]);
}

// ---------------- K1: olf0 = emb * mask (f32 -> bf16) + zero outacc ----------------
__global__ __launch_bounds__(256) void k_prep(const float* __restrict__ emb,
                                              const int* __restrict__ counts,
                                              unsigned short* __restrict__ olf,
                                              float* __restrict__ outacc){
  int bs = blockIdx.x;            // b*28+s
  int b = bs / 28; int s = bs - b*28;
  int e = threadIdx.x;
  olf[(size_t)bs*256 + e] = (s < counts[b]) ? f2b(emb[(size_t)bs*256 + e]) : (unsigned short)0;
  outacc[(size_t)bs*256 + e] = 0.f;
}

// ---------------- K2a: zx = olf_l @ Wih^T  [7168,256]@[256,1024] -> bf16 ----------------
__global__ __launch_bounds__(256) void k_xgemm(const unsigned short* __restrict__ olf,
                                               const unsigned short* __restrict__ Wih,
                                               unsigned short* __restrict__ zx){
  const int tid = threadIdx.x;
  const int wid = tid >> 6, lane = tid & 63, col = lane & 15, quad = lane >> 4;
  const int m0 = blockIdx.x*64 + wid*16;
  short8 af[8];
  #pragma unroll
  for (int kt=0; kt<8; ++kt)
    af[kt] = *(const short8*)&olf[(size_t)(m0 + col)*256 + kt*32 + quad*8];
  #pragma unroll 4
  for (int nt=0; nt<64; ++nt){
    int n = nt*16 + col;
    f32x4 acc = (f32x4){0.f,0.f,0.f,0.f};
    #pragma unroll
    for (int kt=0; kt<8; ++kt){
      short8 bf = *(const short8*)&Wih[((((kt*4 + quad) << 10) + n) << 3)];
      acc = MFMA16(af[kt], bf, acc);
    }
    #pragma unroll
    for (int r=0; r<4; ++r)
      zx[(size_t)(m0 + quad*4 + r)*1024 + n] = f2b(acc[r]);
  }
}

// ---------------- K2b: LSTM recurrence: 16 blocks x 16 scenes, 1024 thr, ping-pong h ----------------
__global__ __launch_bounds__(1024) void k_rec(const unsigned short* __restrict__ zx,
                                              const unsigned short* __restrict__ Whh,
                                              const float* __restrict__ bih,
                                              const float* __restrict__ bhh,
                                              const int* __restrict__ counts,
                                              unsigned short* __restrict__ olf_out){
  __shared__ unsigned short Ab[2][16*264];   // ping-pong h buffers
  const int tid = threadIdx.x;
  const int wv = tid >> 6, lane = tid & 63, col = lane & 15, quad = lane >> 4;
  const int sc0 = blockIdx.x * 16;
  const int u = wv*16 + col;

  float bz[4];
  #pragma unroll
  for (int g=0; g<4; ++g) bz[g] = bih[g*256+u] + bhh[g*256+u];
  int cnt4[4];
  #pragma unroll
  for (int r=0; r<4; ++r) cnt4[r] = counts[sc0 + quad*4 + r];

  float cst[4];
  #pragma unroll
  for (int r=0; r<4; ++r) cst[r] = 0.f;
  for (int i=tid; i<16*264; i+=1024) Ab[0][i] = 0;   // h0 = 0
  __syncthreads();

  for (int t=0; t<28; ++t){
    const int cur = t & 1, nxt = cur ^ 1;
    float zxv[4][4];
    #pragma unroll
    for (int g=0; g<4; ++g){
      #pragma unroll
      for (int r=0; r<4; ++r)
        zxv[g][r] = b2f(zx[((size_t)(sc0 + quad*4 + r)*28 + t)*1024 + g*256 + u]);
    }
    f32x4 acc[4];
    #pragma unroll
    for (int g=0; g<4; ++g) acc[g] = (f32x4){0.f,0.f,0.f,0.f};
    #pragma unroll
    for (int kt=0; kt<8; ++kt){
      short8 a = *(const short8*)&Ab[cur][col*264 + kt*32 + quad*8];
      #pragma unroll
      for (int g=0; g<4; ++g){
        short8 bf = *(const short8*)&Whh[((((kt*4 + quad) << 10) + g*256 + u) << 3)];
        acc[g] = MFMA16(a, bf, acc[g]);
      }
    }
    // no barrier: writes go to Ab[nxt], readers used Ab[cur]
    #pragma unroll
    for (int r=0; r<4; ++r){
      int s = quad*4 + r;
      float zi = acc[0][r] + zxv[0][r] + bz[0];
      float zf = acc[1][r] + zxv[1][r] + bz[1];
      float zg = acc[2][r] + zxv[2][r] + bz[2];
      float zo = acc[3][r] + zxv[3][r] + bz[3];
      float cc = sigm(zf)*cst[r] + sigm(zi)*tanh_f(zg);
      cst[r] = cc;
      float hh = sigm(zo)*tanh_f(cc);
      unsigned short hb = f2b(hh);
      Ab[nxt][s*264 + u] = hb;                              // raw h feeds recurrence
      olf_out[((size_t)(sc0+s)*28 + t)*256 + u] = (t < cnt4[r]) ? hb : (unsigned short)0;
    }
    __syncthreads();   // Ab[nxt] complete before step t+1 reads it
  }
}

// ---------------- K3: A-terms, [21504,256]@[256,512] -> bf16 ----------------
__global__ __launch_bounds__(256) void k_aterm(const unsigned short* __restrict__ olf,
                                               const unsigned short* __restrict__ Wgri,
                                               const unsigned short* __restrict__ Wgrj,
                                               unsigned short* __restrict__ Aout){
  const int tid = threadIdx.x;
  const int wid = tid >> 6, lane = tid & 63, col = lane & 15, quad = lane >> 4;
  const int m0 = blockIdx.x*64 + wid*16;
  short8 af[8];
  #pragma unroll
  for (int kt=0; kt<8; ++kt)
    af[kt] = *(const short8*)&olf[(size_t)(m0 + col)*256 + kt*32 + quad*8];
  #pragma unroll 4
  for (int nt=0; nt<32; ++nt){
    const unsigned short* wb = (nt < 16) ? Wgri : Wgrj;
    int nn = (nt & 15)*16 + col;           // 0..255 within the submatrix
    f32x4 acc = (f32x4){0.f,0.f,0.f,0.f};
    #pragma unroll
    for (int kt=0; kt<8; ++kt){
      short8 bf = *(const short8*)&wb[((((kt*4 + quad) << 8) + nn) << 3)];
      acc = MFMA16(af[kt], bf, acc);
    }
    #pragma unroll
    for (int r=0; r<4; ++r)
      Aout[(size_t)(m0 + quad*4 + r)*512 + nt*16 + col] = f2b(acc[r]);
  }
}

// ---------------- K4: fused per-(scene, j-pair), ping-pong LDS ----------------
// 3584 blocks x 512 thr (8 waves). Row p = i*2 + jc (i<28, jc<2) -> 56 rows
// padded to 64. Wave wv owns cols wv*32..+31 for all 64 rows. Xa/Yb 2x32KB.
// Weights fragment-major, N=256.
#define GEMM_TILE64(SRC, WPTR)                                                      \
  {                                                                                 \
    _Pragma("unroll")                                                               \
    for (int rf=0; rf<4; ++rf){ Ya[rf][0]=(f32x4){0.f,0.f,0.f,0.f};                 \
                                Ya[rf][1]=(f32x4){0.f,0.f,0.f,0.f}; }               \
    _Pragma("unroll 1")                                                             \
    for (int kc=0; kc<4; ++kc){                                                     \
      short8 av[2][4], bv[2][2];                                                    \
      _Pragma("unroll")                                                             \
      for (int u=0; u<2; ++u){                                                      \
        int kt = kc*2 + u; int c = kt*4 + quad;                                     \
        _Pragma("unroll")                                                           \
        for (int rf=0; rf<4; ++rf)                                                  \
          av[u][rf] = *(const short8*)&(SRC)[xchunk(rf*16+col, c)];                 \
        bv[u][0] = *(const short8*)&(WPTR)[(((c << 8) + nbase + col) << 3)];        \
        bv[u][1] = *(const short8*)&(WPTR)[(((c << 8) + nbase + 16 + col) << 3)];   \
      }                                                                             \
      _Pragma("unroll")                                                             \
      for (int u=0; u<2; ++u){                                                      \
        _Pragma("unroll")                                                           \
        for (int rf=0; rf<4; ++rf){                                                 \
          Ya[rf][0] = MFMA16(av[u][rf], bv[u][0], Ya[rf][0]);                       \
          Ya[rf][1] = MFMA16(av[u][rf], bv[u][1], Ya[rf][1]);                       \
        }                                                                           \
      }                                                                             \
    }                                                                               \
  }

__global__ __launch_bounds__(512) void k_mega(
    const float* __restrict__ centers, const int* __restrict__ counts,
    const float* __restrict__ Wr, const float* __restrict__ br,
    const unsigned short* __restrict__ Wgrr, const float* __restrict__ bgr,
    const unsigned short* __restrict__ Wbc, const float* __restrict__ bbc,
    const float* __restrict__ alpha,
    const unsigned short* __restrict__ Wesa, const float* __restrict__ besa,
    const float* __restrict__ wmean, const float* __restrict__ bmu,
    const unsigned short* __restrict__ Aterm, float* __restrict__ outacc){
  __shared__ unsigned short Xa[64*256];    // rlf; rows 56..63 pad -> stats later
  __shared__ unsigned short Yb[64*256];    // rlf_lin / resa
  float* lseBp = (float*)&Xa[56*256];      // 512 f32 [jc*256+o]
  float* gsbp  = (float*)&Xa[60*256];      // 64 f32 per row p
  float* lseGp = (float*)&Xa[60*256+128];  // 2 f32 per jc
  const int tid = threadIdx.x;
  const int wv = tid >> 6;          // 0..7 -> col slice
  const int lane = tid & 63, col = lane & 15, quad = lane >> 4;
  const int b = blockIdx.x / 14, jt = blockIdx.x - b*14;   // j = jt*2 + jc
  const int cb = counts[b];
  const int nbase = wv*32;

  float av_ = alpha[0];
  float tv = sigm(av_);
  float c1 = (1.f-tv)*(1.f-tv) + tv*tv;
  float c2 = 2.f*tv*(1.f-tv);

  int pis[4][4], pjs[4][4]; float pv[4][4];
  #pragma unroll
  for (int rf=0; rf<4; ++rf){
    #pragma unroll
    for (int r=0; r<4; ++r){
      int row = rf*16 + quad*4 + r;
      int i = row >> 1;
      pis[rf][r] = (i < 27) ? i : 27;
      pjs[rf][r] = jt*2 + (row & 1);
      pv[rf][r] = (row < 56 && i < cb && pjs[rf][r] < cb) ? 1.f : 0.f;
    }
  }
  // S0: rlf0[row] -> Xa ; pad rows = 0
  {
    int m = tid >> 3, sub = tid & 7;   // m 0..63, 32 cols each
    int i = m >> 1, j = jt*2 + (m & 1);
    bool valid = (m < 56);
    float mi = (valid && i < cb) ? 1.f : 0.f;
    float mj = (valid && j < cb) ? 1.f : 0.f;
    const float* ci = centers + (b*28 + (valid ? i : 0))*3;
    const float* cj = centers + (b*28 + j)*3;
    float dx = mi*ci[0] - mj*cj[0];
    float dy = mi*ci[1] - mj*cj[1];
    float dz = mi*ci[2] - mj*cj[2];
    for (int e = sub*32; e < sub*32 + 32; ++e){
      float v = valid ? (dx*Wr[e*3] + dy*Wr[e*3+1] + dz*Wr[e*3+2] + br[e]) : 0.f;
      Xa[xsw(m, e)] = f2b(v);
    }
  }
  __syncthreads();

  f32x4 Ya[4][2];
  #pragma unroll 1
  for (int l=0; l<3; ++l){
    // GEMM1: rlf(Xa) @ Wgr_r^T  -- then S2 writes Yb (no barrier in between)
    GEMM_TILE64(Xa, Wgrr);
    // S2: rlf_lin = Y + A_i + A_j + bgr -> Yb (bf16)
    const int lb = (l*7168 + b*28)*512;
    #pragma unroll
    for (int nt=0; nt<2; ++nt){
      int n = nbase + nt*16 + col;
      float bg = bgr[n];
      #pragma unroll
      for (int rf=0; rf<4; ++rf){
        #pragma unroll
        for (int r=0; r<4; ++r){
          float v = Ya[rf][nt][r] + bg
                  + b2f(Aterm[lb + pis[rf][r]*512 + n])
                  + b2f(Aterm[lb + pjs[rf][r]*512 + 256 + n]);
          Yb[xsw(rf*16 + quad*4 + r, n)] = f2b(v);
        }
      }
    }
    __syncthreads();   // Yb complete before GEMM2 reads it
    // GEMM2: rlf_lin(Yb) @ Wbc^T -- then S4 writes Xa (no barrier in between)
    GEMM_TILE64(Yb, Wbc);
    // S4: rlf = tanh(c1*rlf_lin + c2*(CP+bbc)) * pv -> Xa
    #pragma unroll
    for (int nt=0; nt<2; ++nt){
      int n = nbase + nt*16 + col;
      float bb = bbc[n];
      #pragma unroll
      for (int rf=0; rf<4; ++rf){
        #pragma unroll
        for (int r=0; r<4; ++r){
          int off = xsw(rf*16 + quad*4 + r, n);
          float rl = b2f(Yb[off]);
          float bez = c1*rl + c2*(Ya[rf][nt][r] + bb);
          Xa[off] = f2b(tanh_f(bez) * pv[rf][r]);
        }
      }
    }
    __syncthreads();   // Xa complete before next GEMM1; fences Yb readers vs next S2
  }
  // S5: resa = rlf(Xa) @ Wesa^T + besa -> Yb
  GEMM_TILE64(Xa, Wesa);
  #pragma unroll
  for (int nt=0; nt<2; ++nt){
    int n = nbase + nt*16 + col;
    float be = besa[n];
    #pragma unroll
    for (int rf=0; rf<4; ++rf){
      #pragma unroll
      for (int r=0; r<4; ++r)
        Yb[xsw(rf*16 + quad*4 + r, n)] = f2b(Ya[rf][nt][r] + be);
    }
  }
  __syncthreads();   // resa (Yb) complete; Xa dead -> stats go into Xa pads
  // gscore per row (rows < 56) + lseB per (jc,o), all read Yb.
  // resa is tanh-bounded -> direct sum-exp (no max pass) is overflow-safe.
  {
    int m = tid >> 3, sub = tid & 7;   // 8 threads per row, 32 cols each
    if (m < 56){
      float s = 0.f;
      for (int e = sub*32; e < sub*32 + 32; ++e)
        s += b2f(Yb[xsw(m, e)]) * wmean[e];
      s += __shfl_xor(s, 1, 64);
      s += __shfl_xor(s, 2, 64);
      s += __shfl_xor(s, 4, 64);
      if (sub == 0)
        gsbp[m] = s + (bmu[0] + bmu[1] + bmu[2])*(1.f/3.f);
    }
  }
  {
    int jc = tid >> 8, o = tid & 255;  // all 512 threads
    float se = 0.f;
    for (int i=0;i<28;++i) se += __expf(b2f(Yb[xsw(i*2+jc, o)]));
    lseBp[jc*256 + o] = __logf(se);
  }
  __syncthreads();
  if (tid < 2){
    int jc = tid;
    float se = 0.f;
    for (int i=0;i<28;++i) se += __expf(gsbp[i*2+jc]);
    lseGp[jc] = __logf(se);
  }
  __syncthreads();
  // output contribution of this block's 2 j's: one atomicAdd per (i,o)
  for (int it = tid; it < 7168; it += 512){
    int i = it >> 8, o = it & 255;
    float s = 0.f;
    #pragma unroll
    for (int jc=0; jc<2; ++jc){
      int row = i*2 + jc;
      float v = b2f(Yb[xsw(row, o)]);
      float a = 0.5f*__expf(v - lseBp[jc*256+o]) + 0.5f*__expf(gsbp[row] - lseGp[jc]);
      s += a * v;
    }
    atomicAdd(&outacc[((size_t)b*28 + i)*256 + o], s);
  }
}

// ---------------- K5: mask + write f32 ----------------
__global__ __launch_bounds__(256) void k_out(const float* __restrict__ outacc,
                                             const int* __restrict__ counts,
                                             float* __restrict__ out){
  int b = blockIdx.x / 28, i = blockIdx.x - b*28, o = threadIdx.x;
  float acc = outacc[(size_t)blockIdx.x*256 + o];
  if (i >= counts[b]) acc = 0.f;
  out[(size_t)blockIdx.x*256 + o] = acc;
}

extern "C" void kernel_launch(void* const* d_in, const int* in_sizes, int n_in,
                              void* d_out, int out_size, void* d_ws, size_t ws_size,
                              hipStream_t stream){
  const float* centers = (const float*)d_in[0];
  const float* emb     = (const float*)d_in[1];
  const int*   counts  = (const int*)d_in[2];
  const float* Wr      = (const float*)d_in[3];
  const float* br      = (const float*)d_in[4];
  const float* Wih     = (const float*)d_in[5];
  const float* Whh     = (const float*)d_in[6];
  const float* bih     = (const float*)d_in[7];
  const float* bhh     = (const float*)d_in[8];
  const float* Wgr     = (const float*)d_in[9];
  const float* bgr     = (const float*)d_in[10];
  const float* Wbc     = (const float*)d_in[11];
  const float* bbc     = (const float*)d_in[12];
  const float* alpha   = (const float*)d_in[13];
  const float* Wesa    = (const float*)d_in[14];
  const float* besa    = (const float*)d_in[15];
  const float* Wmu     = (const float*)d_in[16];
  const float* bmu     = (const float*)d_in[17];
  // d_in[18], d_in[19] (Wlv, blv) are dead at eval time.

  // ws layout (42,075,136 bytes total):
  unsigned short* olf    = (unsigned short*)d_ws;                      // 3*7168*256 bf16 = 11,010,048 B
  unsigned short* At     = (unsigned short*)((char*)d_ws + 11010048);  // 3*7168*512 bf16 = 22,020,096 B
  unsigned short* zx     = At;                                         // 7168*1024 bf16 (aliases At)
  float*          outacc = (float*)((char*)d_ws + 33030144);           // 7168*256 f32 = 7,340,032 B
  unsigned short* wcv    = (unsigned short*)((char*)d_ws + 40370176);  // 851,968 bf16 = 1,703,936 B
  float*          wmean  = (float*)((char*)d_ws + 42074112);           // 256 f32 = 1,024 B
  unsigned short* cWih  = wcv;            // 262144 (N=1024)
  unsigned short* cWhh  = wcv + 262144;   // 262144 (N=1024)
  unsigned short* cWgri = wcv + 524288;   // 65536  (N=256)
  unsigned short* cWgrj = wcv + 589824;   // 65536  (N=256)
  unsigned short* cWgrr = wcv + 655360;   // 65536  (N=256)
  unsigned short* cWbc  = wcv + 720896;   // 65536  (N=256)
  unsigned short* cWesa = wcv + 786432;   // 65536  (N=256)
  float* outp = (float*)d_out;

  hipLaunchKernelGGL(k_repack7, dim3(3329), dim3(256), 0, stream,
                     Wih, Whh, Wgr, Wbc, Wesa, Wmu, wcv, wmean);

  hipLaunchKernelGGL(k_prep, dim3(7168), dim3(256), 0, stream, emb, counts, olf, outacc);
  // LSTM pass 1: olf0 -> olf1
  hipLaunchKernelGGL(k_xgemm, dim3(112), dim3(256), 0, stream, olf, cWih, zx);
  hipLaunchKernelGGL(k_rec,   dim3(16),  dim3(1024), 0, stream, zx, cWhh, bih, bhh, counts,
                     olf + (size_t)7168*256);
  // LSTM pass 2: olf1 -> olf2
  hipLaunchKernelGGL(k_xgemm, dim3(112), dim3(256), 0, stream, olf + (size_t)7168*256, cWih, zx);
  hipLaunchKernelGGL(k_rec,   dim3(16),  dim3(1024), 0, stream, zx, cWhh, bih, bhh, counts,
                     olf + (size_t)2*7168*256);
  hipLaunchKernelGGL(k_aterm, dim3(336), dim3(256), 0, stream, olf, cWgri, cWgrj, At);
  hipLaunchKernelGGL(k_mega,  dim3(3584), dim3(512), 0, stream,
                     centers, counts, Wr, br, cWgrr, bgr, cWbc, bbc, alpha,
                     cWesa, besa, wmean, bmu, At, outacc);
  hipLaunchKernelGGL(k_out,   dim3(7168), dim3(256), 0, stream, outacc, counts, outp);
}